// Round 1
// baseline (3582.057 us; speedup 1.0000x reference)
//
#include <hip/hip_runtime.h>
#include <math.h>

#define BB 2
#define SS 2048
#define DD 2048
#define QH 16
#define NKV 4
#define HD 128
#define REP 4           // QH / NKV
#define NEG_INF_F (-1e9f)

// ---------------------------------------------------------------------------
// Kernel 1: fused QKV projection.
// Logical GEMM: x[B*S, D] @ W[D, 3072]  where cols [0,2048)=q, [2048,2560)=k,
// [2560,3072)=v. Each 64-wide col tile lies inside one head (64 | 128).
// q out: [B,S,QH,HD] ; k,v out: [B,S,NKV,HD]
// ---------------------------------------------------------------------------
__global__ __launch_bounds__(256) void qkv_kernel(
    const float* __restrict__ x,
    const float* __restrict__ Wq, const float* __restrict__ Wk,
    const float* __restrict__ Wv,
    float* __restrict__ qo, float* __restrict__ ko, float* __restrict__ vo)
{
    const int cb = blockIdx.x * 64;   // global col base in [0, 3072)
    const int m0 = blockIdx.y * 64;   // row base in [0, 4096)

    const float* wbase;
    float* obase;
    int ostride;
    if (cb < 2048) {                       // q region
        const int head = cb >> 7, h0 = cb & 127;
        wbase   = Wq + (size_t)head * (DD * HD) + h0;
        obase   = qo + (size_t)m0 * (QH * HD) + cb;
        ostride = QH * HD;
    } else if (cb < 2560) {                // k region
        const int c2 = cb - 2048;
        const int head = c2 >> 7, h0 = c2 & 127;
        wbase   = Wk + (size_t)head * (DD * HD) + h0;
        obase   = ko + (size_t)m0 * (NKV * HD) + c2;
        ostride = NKV * HD;
    } else {                               // v region
        const int c3 = cb - 2560;
        const int head = c3 >> 7, h0 = c3 & 127;
        wbase   = Wv + (size_t)head * (DD * HD) + h0;
        obase   = vo + (size_t)m0 * (NKV * HD) + c3;
        ostride = NKV * HD;
    }

    __shared__ float As[16][65];   // [kk][row]
    __shared__ float Ws[16][65];   // [kk][col]

    const int tid = threadIdx.x;
    const int tx = tid & 15, ty = tid >> 4;

    float acc[4][4] = {};

    for (int k0 = 0; k0 < DD; k0 += 16) {
        #pragma unroll
        for (int it = 0; it < 4; ++it) {
            const int idx = tid + 256 * it;          // 1024 elems
            const int kk = idx & 15, r = idx >> 4;   // consecutive tid -> consecutive kk
            As[kk][r] = x[(size_t)(m0 + r) * DD + k0 + kk];
        }
        #pragma unroll
        for (int it = 0; it < 4; ++it) {
            const int idx = tid + 256 * it;
            const int c = idx & 63, kk = idx >> 6;   // consecutive tid -> consecutive col
            Ws[kk][c] = wbase[(size_t)(k0 + kk) * HD + c];
        }
        __syncthreads();
        #pragma unroll
        for (int kk = 0; kk < 16; ++kk) {
            float a[4], b[4];
            #pragma unroll
            for (int i = 0; i < 4; ++i) a[i] = As[kk][ty + 16 * i];
            #pragma unroll
            for (int j = 0; j < 4; ++j) b[j] = Ws[kk][tx + 16 * j];
            #pragma unroll
            for (int i = 0; i < 4; ++i)
                #pragma unroll
                for (int j = 0; j < 4; ++j) acc[i][j] += a[i] * b[j];
        }
        __syncthreads();
    }

    #pragma unroll
    for (int i = 0; i < 4; ++i)
        #pragma unroll
        for (int j = 0; j < 4; ++j)
            obase[(size_t)(ty + 16 * i) * ostride + tx + 16 * j] = acc[i][j];
}

// ---------------------------------------------------------------------------
// Kernel 2: RoPE in-place on q and k. One thread per (b,s,head,freq) pair.
// ---------------------------------------------------------------------------
__global__ void rope_kernel(float* __restrict__ q, float* __restrict__ k,
                            const int* __restrict__ positions)
{
    const int qpairs = BB * SS * QH * 64;
    const int kpairs = BB * SS * NKV * 64;
    int idx = blockIdx.x * blockDim.x + threadIdx.x;
    float* base;
    int nh;
    if (idx < qpairs) { base = q; nh = QH; }
    else {
        idx -= qpairs;
        if (idx >= kpairs) return;
        base = k; nh = NKV;
    }
    const int hh   = idx & 63;
    const int rest = idx >> 6;                 // (b*S + s)*nh + head
    const int head = rest % nh;
    const int bs   = rest / nh;                // b*S + s
    const int s    = bs % SS;

    float* p = base + ((size_t)bs * nh + head) * HD;
    const float pos = (float)positions[s];
    const float inv_ts = powf(10000.0f, -(float)hh * (1.0f / 64.0f));
    const float angle = pos * inv_ts;
    const float sn = sinf(angle), cs = cosf(angle);
    const float x1 = p[hh], x2 = p[hh + 64];
    p[hh]      = x1 * cs - x2 * sn;
    p[hh + 64] = x2 * cs + x1 * sn;
}

// ---------------------------------------------------------------------------
// Kernel 3: causal flash attention with GQA.
// Block = 256 threads handles one (b, qh, 32-row q tile); iterates 32-col
// K/V tiles with online softmax. Thread (tx,ty): tx in [0,32) = t column,
// ty in [0,8); rows handled = ty + 8i (i<4); O cols = tx + 32j (j<4).
// ---------------------------------------------------------------------------
__global__ __launch_bounds__(256) void attn_kernel(
    const float* __restrict__ q, const float* __restrict__ k,
    const float* __restrict__ v, float* __restrict__ o)
{
    const int s0 = blockIdx.x * 32;
    const int bh = blockIdx.y;
    const int b  = bh / QH, qh = bh % QH;
    const int n  = qh / REP;

    const int tid = threadIdx.x;
    const int tx = tid & 31, ty = tid >> 5;

    __shared__ float Qs[32][129];
    __shared__ float Ks[32][129];
    __shared__ float Vs[32][129];
    __shared__ float Ps[32][33];

    for (int idx = tid; idx < 32 * 128; idx += 256) {
        const int r = idx >> 7, h = idx & 127;
        Qs[r][h] = q[((size_t)(b * SS + s0 + r) * QH + qh) * HD + h];
    }

    float acc[4][4] = {};
    float mrow[4], lrow[4];
    #pragma unroll
    for (int i = 0; i < 4; ++i) { mrow[i] = -1e30f; lrow[i] = 0.0f; }
    const float scale = 0.08838834764831845f;   // 1/sqrt(128)

    for (int t0 = 0; t0 <= s0; t0 += 32) {
        __syncthreads();   // previous tile's PV reads done before overwrite
        for (int idx = tid; idx < 32 * 128; idx += 256) {
            const int r = idx >> 7, h = idx & 127;
            const size_t ga = ((size_t)(b * SS + t0 + r) * NKV + n) * HD + h;
            Ks[r][h] = k[ga];
            Vs[r][h] = v[ga];
        }
        __syncthreads();

        // QK^T: thread computes score(rows ty+8i, col tx)
        float sc[4] = {0.f, 0.f, 0.f, 0.f};
        for (int h = 0; h < 128; ++h) {
            const float kv = Ks[tx][h];
            #pragma unroll
            for (int i = 0; i < 4; ++i) sc[i] += Qs[ty + 8 * i][h] * kv;
        }

        const bool diag = (t0 + 31 > s0);
        #pragma unroll
        for (int i = 0; i < 4; ++i) {
            const int r = ty + 8 * i;
            float sv = sc[i] * scale;
            if (diag && (t0 + tx > s0 + r)) sv = NEG_INF_F;
            // row max over the 32 tx lanes
            float tm = sv;
            #pragma unroll
            for (int off = 1; off < 32; off <<= 1)
                tm = fmaxf(tm, __shfl_xor(tm, off));
            const float mnew  = fmaxf(mrow[i], tm);
            const float alpha = __expf(mrow[i] - mnew);
            const float pv    = __expf(sv - mnew);
            float ps = pv;
            #pragma unroll
            for (int off = 1; off < 32; off <<= 1)
                ps += __shfl_xor(ps, off);
            lrow[i] = lrow[i] * alpha + ps;
            mrow[i] = mnew;
            #pragma unroll
            for (int j = 0; j < 4; ++j) acc[i][j] *= alpha;
            Ps[r][tx] = pv;
        }
        __syncthreads();

        // PV: acc[i][j] += sum_t Ps[r][t] * Vs[t][tx+32j]
        for (int t = 0; t < 32; ++t) {
            float vv[4];
            #pragma unroll
            for (int j = 0; j < 4; ++j) vv[j] = Vs[t][tx + 32 * j];
            #pragma unroll
            for (int i = 0; i < 4; ++i) {
                const float p = Ps[ty + 8 * i][t];
                #pragma unroll
                for (int j = 0; j < 4; ++j) acc[i][j] += p * vv[j];
            }
        }
    }

    #pragma unroll
    for (int i = 0; i < 4; ++i) {
        const float invl = 1.0f / lrow[i];
        const int r = s0 + ty + 8 * i;
        #pragma unroll
        for (int j = 0; j < 4; ++j)
            o[((size_t)(b * SS + r) * QH + qh) * HD + tx + 32 * j] =
                acc[i][j] * invl;
    }
}

// ---------------------------------------------------------------------------
// Kernel 4: output projection. o_pre[B*S, 2048] @ Wo[2048, 2048] (Wo is
// [Q,H,D] row-major = [2048, 2048], k index = qh*128+h — contiguous).
// ---------------------------------------------------------------------------
__global__ __launch_bounds__(256) void oproj_kernel(
    const float* __restrict__ A, const float* __restrict__ W,
    float* __restrict__ C)
{
    const int cb = blockIdx.x * 64;
    const int m0 = blockIdx.y * 64;

    __shared__ float As[16][65];
    __shared__ float Ws[16][65];

    const int tid = threadIdx.x;
    const int tx = tid & 15, ty = tid >> 4;

    float acc[4][4] = {};

    for (int k0 = 0; k0 < 2048; k0 += 16) {
        #pragma unroll
        for (int it = 0; it < 4; ++it) {
            const int idx = tid + 256 * it;
            const int kk = idx & 15, r = idx >> 4;
            As[kk][r] = A[(size_t)(m0 + r) * 2048 + k0 + kk];
        }
        #pragma unroll
        for (int it = 0; it < 4; ++it) {
            const int idx = tid + 256 * it;
            const int c = idx & 63, kk = idx >> 6;
            Ws[kk][c] = W[(size_t)(k0 + kk) * 2048 + cb + c];
        }
        __syncthreads();
        #pragma unroll
        for (int kk = 0; kk < 16; ++kk) {
            float a[4], b[4];
            #pragma unroll
            for (int i = 0; i < 4; ++i) a[i] = As[kk][ty + 16 * i];
            #pragma unroll
            for (int j = 0; j < 4; ++j) b[j] = Ws[kk][tx + 16 * j];
            #pragma unroll
            for (int i = 0; i < 4; ++i)
                #pragma unroll
                for (int j = 0; j < 4; ++j) acc[i][j] += a[i] * b[j];
        }
        __syncthreads();
    }

    #pragma unroll
    for (int i = 0; i < 4; ++i)
        #pragma unroll
        for (int j = 0; j < 4; ++j)
            C[(size_t)(m0 + ty + 16 * i) * 2048 + cb + tx + 16 * j] = acc[i][j];
}

// ---------------------------------------------------------------------------
extern "C" void kernel_launch(void* const* d_in, const int* in_sizes, int n_in,
                              void* d_out, int out_size, void* d_ws,
                              size_t ws_size, hipStream_t stream)
{
    const float* x         = (const float*)d_in[0];
    const int*   positions = (const int*)d_in[1];
    const float* Wq        = (const float*)d_in[2];
    const float* Wk        = (const float*)d_in[3];
    const float* Wv        = (const float*)d_in[4];
    const float* Wo        = (const float*)d_in[5];
    float* out = (float*)d_out;

    // workspace layout (floats): q | k | v | o_pre  = 80 MB total
    float* qb = (float*)d_ws;
    float* kb = qb + (size_t)BB * SS * QH  * HD;   // +8,388,608
    float* vb = kb + (size_t)BB * SS * NKV * HD;   // +2,097,152
    float* ob = vb + (size_t)BB * SS * NKV * HD;   // +2,097,152

    dim3 g1(3072 / 64, (BB * SS) / 64);            // (48, 64)
    qkv_kernel<<<g1, 256, 0, stream>>>(x, Wq, Wk, Wv, qb, kb, vb);

    const int pairs = BB * SS * (QH + NKV) * 64;
    rope_kernel<<<(pairs + 255) / 256, 256, 0, stream>>>(qb, kb, positions);

    dim3 g2(SS / 32, BB * QH);                     // (64, 32)
    attn_kernel<<<g2, 256, 0, stream>>>(qb, kb, vb, ob);

    dim3 g3(2048 / 64, (BB * SS) / 64);            // (32, 64)
    oproj_kernel<<<g3, 256, 0, stream>>>(ob, Wo, out);
}

// Round 2
// 1903.699 us; speedup vs baseline: 1.8816x; 1.8816x over previous
//
#include <hip/hip_runtime.h>
#include <math.h>

#define BB 2
#define SS 2048
#define DD 2048
#define QH 16
#define NKV 4
#define HD 128
#define REP 4           // QH / NKV
#define NEG_INF_F (-1e9f)

typedef __bf16 bfrag __attribute__((ext_vector_type(8)));   // 4 VGPRs
typedef float  ffrag __attribute__((ext_vector_type(4)));   // 4 VGPRs

__device__ inline unsigned short f2bf(float f) {
    unsigned u = __builtin_bit_cast(unsigned, f);
    u += 0x7fff + ((u >> 16) & 1);          // round-to-nearest-even
    return (unsigned short)(u >> 16);
}

__device__ inline bfrag ld_frag(const unsigned short* p) {
    uint4 u = *(const uint4*)p;
    return __builtin_bit_cast(bfrag, u);
}

// ---------------------------------------------------------------------------
// Kernel 1: fused QKV projection (fp32 GEMM). q,k written fp32 (rope input);
// v written directly as bf16 (attention input).
// ---------------------------------------------------------------------------
__global__ __launch_bounds__(256) void qkv_kernel(
    const float* __restrict__ x,
    const float* __restrict__ Wq, const float* __restrict__ Wk,
    const float* __restrict__ Wv,
    float* __restrict__ qo, float* __restrict__ ko,
    unsigned short* __restrict__ vo)
{
    const int cb = blockIdx.x * 64;   // global col base in [0, 3072)
    const int m0 = blockIdx.y * 64;   // row base in [0, 4096)

    const float* wbase;
    float* obase = nullptr;
    unsigned short* obase_bf = nullptr;
    int ostride;
    if (cb < 2048) {                       // q region
        const int head = cb >> 7, h0 = cb & 127;
        wbase   = Wq + (size_t)head * (DD * HD) + h0;
        obase   = qo + (size_t)m0 * (QH * HD) + cb;
        ostride = QH * HD;
    } else if (cb < 2560) {                // k region
        const int c2 = cb - 2048;
        const int head = c2 >> 7, h0 = c2 & 127;
        wbase   = Wk + (size_t)head * (DD * HD) + h0;
        obase   = ko + (size_t)m0 * (NKV * HD) + c2;
        ostride = NKV * HD;
    } else {                               // v region -> bf16
        const int c3 = cb - 2560;
        const int head = c3 >> 7, h0 = c3 & 127;
        wbase    = Wv + (size_t)head * (DD * HD) + h0;
        obase_bf = vo + (size_t)m0 * (NKV * HD) + c3;
        ostride  = NKV * HD;
    }

    __shared__ float As[16][65];   // [kk][row]
    __shared__ float Ws[16][65];   // [kk][col]

    const int tid = threadIdx.x;
    const int tx = tid & 15, ty = tid >> 4;

    float acc[4][4] = {};

    for (int k0 = 0; k0 < DD; k0 += 16) {
        #pragma unroll
        for (int it = 0; it < 4; ++it) {
            const int idx = tid + 256 * it;
            const int kk = idx & 15, r = idx >> 4;
            As[kk][r] = x[(size_t)(m0 + r) * DD + k0 + kk];
        }
        #pragma unroll
        for (int it = 0; it < 4; ++it) {
            const int idx = tid + 256 * it;
            const int c = idx & 63, kk = idx >> 6;
            Ws[kk][c] = wbase[(size_t)(k0 + kk) * HD + c];
        }
        __syncthreads();
        #pragma unroll
        for (int kk = 0; kk < 16; ++kk) {
            float a[4], b[4];
            #pragma unroll
            for (int i = 0; i < 4; ++i) a[i] = As[kk][ty + 16 * i];
            #pragma unroll
            for (int j = 0; j < 4; ++j) b[j] = Ws[kk][tx + 16 * j];
            #pragma unroll
            for (int i = 0; i < 4; ++i)
                #pragma unroll
                for (int j = 0; j < 4; ++j) acc[i][j] += a[i] * b[j];
        }
        __syncthreads();
    }

    if (obase_bf) {
        #pragma unroll
        for (int i = 0; i < 4; ++i)
            #pragma unroll
            for (int j = 0; j < 4; ++j)
                obase_bf[(size_t)(ty + 16 * i) * ostride + tx + 16 * j] =
                    f2bf(acc[i][j]);
    } else {
        #pragma unroll
        for (int i = 0; i < 4; ++i)
            #pragma unroll
            for (int j = 0; j < 4; ++j)
                obase[(size_t)(ty + 16 * i) * ostride + tx + 16 * j] = acc[i][j];
    }
}

// ---------------------------------------------------------------------------
// Kernel 2: RoPE on q,k (fp32 in) fused with bf16 cast (bf16 out).
// One thread per (b,s,head,freq) pair.
// ---------------------------------------------------------------------------
__global__ void rope_cast_kernel(const float* __restrict__ qf,
                                 const float* __restrict__ kf,
                                 unsigned short* __restrict__ qb,
                                 unsigned short* __restrict__ kb,
                                 const int* __restrict__ positions)
{
    const int qpairs = BB * SS * QH * 64;
    const int kpairs = BB * SS * NKV * 64;
    int idx = blockIdx.x * blockDim.x + threadIdx.x;
    const float* src;
    unsigned short* dst;
    int nh;
    if (idx < qpairs) { src = qf; dst = qb; nh = QH; }
    else {
        idx -= qpairs;
        if (idx >= kpairs) return;
        src = kf; dst = kb; nh = NKV;
    }
    const int hh   = idx & 63;
    const int rest = idx >> 6;                 // (b*S + s)*nh + head
    const int head = rest % nh;
    const int bs   = rest / nh;
    const int s    = bs % SS;

    const size_t base = ((size_t)bs * nh + head) * HD;
    const float pos = (float)positions[s];
    const float inv_ts = powf(10000.0f, -(float)hh * (1.0f / 64.0f));
    const float angle = pos * inv_ts;
    const float sn = sinf(angle), cs = cosf(angle);
    const float x1 = src[base + hh], x2 = src[base + hh + 64];
    dst[base + hh]      = f2bf(x1 * cs - x2 * sn);
    dst[base + hh + 64] = f2bf(x2 * cs + x1 * sn);
}

// ---------------------------------------------------------------------------
// Kernel 3: causal flash attention, bf16 MFMA (16x16x32), GQA.
// Block = 256 threads = 4 waves. BM=64 q-rows (16/wave), BN=64 K/V tile.
// Q fragments in registers; K row-major LDS; V transposed in LDS; P through
// per-wave LDS (C-layout -> A-layout). fp32 online softmax + accumulators.
// ---------------------------------------------------------------------------
#define BM 64
#define BN 64
#define KPAD 136   // 128 + 8 bf16 pad
#define VPAD 72    // 64  + 8 bf16 pad

__global__ __launch_bounds__(256) void attn_kernel(
    const unsigned short* __restrict__ qb,
    const unsigned short* __restrict__ kb,
    const unsigned short* __restrict__ vb,
    float* __restrict__ o)
{
    const int s0 = blockIdx.x * BM;
    const int bh = blockIdx.y;
    const int b  = bh / QH, qh = bh % QH;
    const int n  = qh / REP;

    const int tid  = threadIdx.x;
    const int w    = tid >> 6;       // wave 0..3
    const int lane = tid & 63;
    const int l16  = lane & 15;
    const int quad = lane >> 4;      // 0..3

    __shared__ unsigned short Ks[BN][KPAD];      // [key][h]
    __shared__ unsigned short Vt[HD][VPAD];      // [h][key]
    __shared__ unsigned short Ps[4][16][VPAD];   // per-wave P: [row][key]

    // --- preload Q fragments (A-layout: m=l16, k=quad*8+j within 32-chunk)
    bfrag qf[4];
    {
        const int qrow = s0 + w * 16 + l16;
        const unsigned short* qp =
            qb + ((size_t)(b * SS + qrow) * QH + qh) * HD + quad * 8;
        #pragma unroll
        for (int c = 0; c < 4; ++c)
            qf[c] = ld_frag(qp + c * 32);
    }

    ffrag oacc[8];
    #pragma unroll
    for (int t = 0; t < 8; ++t) oacc[t] = (ffrag){0.f, 0.f, 0.f, 0.f};
    float mr[4], lr[4];
    #pragma unroll
    for (int r = 0; r < 4; ++r) { mr[r] = -1e30f; lr[r] = 0.0f; }
    const float scale = 0.08838834764831845f;   // 1/sqrt(128)
    const int rbase = s0 + w * 16 + quad * 4;   // this lane's row for reg 0

    for (int t0 = 0; t0 <= s0; t0 += BN) {
        __syncthreads();   // previous iteration's LDS reads done
        // --- stage K (row-major) and V (transposed), bf16
        for (int idx = tid; idx < BN * 16; idx += 256) {
            const int r = idx >> 4, seg = idx & 15;
            const size_t ga =
                ((size_t)(b * SS + t0 + r) * NKV + n) * HD + seg * 8;
            uint4 kv = *(const uint4*)(kb + ga);
            *(uint4*)&Ks[r][seg * 8] = kv;
            uint4 vv = *(const uint4*)(vb + ga);
            const unsigned short* vs = (const unsigned short*)&vv;
            #pragma unroll
            for (int j = 0; j < 8; ++j) Vt[seg * 8 + j][r] = vs[j];
        }
        __syncthreads();

        // --- QK^T: 4 n-tiles x 4 K-chunks
        ffrag sc[4];
        #pragma unroll
        for (int t = 0; t < 4; ++t) sc[t] = (ffrag){0.f, 0.f, 0.f, 0.f};
        #pragma unroll
        for (int c = 0; c < 4; ++c) {
            #pragma unroll
            for (int t = 0; t < 4; ++t) {
                bfrag kfr = ld_frag(&Ks[t * 16 + l16][c * 32 + quad * 8]);
                sc[t] = __builtin_amdgcn_mfma_f32_16x16x32_bf16(
                    qf[c], kfr, sc[t], 0, 0, 0);
            }
        }

        // --- mask + online softmax (C layout: row=quad*4+reg, col=l16)
        float sv[4][4];   // [t][reg]
        const bool need_mask = (t0 + BN - 1) > rbase;
        #pragma unroll
        for (int t = 0; t < 4; ++t) {
            const int col = t0 + t * 16 + l16;
            #pragma unroll
            for (int r = 0; r < 4; ++r) {
                float s = sc[t][r] * scale;
                if (need_mask && (col > rbase + r)) s = NEG_INF_F;
                sv[t][r] = s;
            }
        }
        #pragma unroll
        for (int r = 0; r < 4; ++r) {
            float tm = fmaxf(fmaxf(sv[0][r], sv[1][r]),
                             fmaxf(sv[2][r], sv[3][r]));
            #pragma unroll
            for (int off = 1; off < 16; off <<= 1)
                tm = fmaxf(tm, __shfl_xor(tm, off));
            const float mnew  = fmaxf(mr[r], tm);
            const float alpha = __expf(mr[r] - mnew);
            float p0 = __expf(sv[0][r] - mnew);
            float p1 = __expf(sv[1][r] - mnew);
            float p2 = __expf(sv[2][r] - mnew);
            float p3 = __expf(sv[3][r] - mnew);
            float ps = p0 + p1 + p2 + p3;
            #pragma unroll
            for (int off = 1; off < 16; off <<= 1)
                ps += __shfl_xor(ps, off);
            lr[r] = lr[r] * alpha + ps;
            mr[r] = mnew;
            #pragma unroll
            for (int t = 0; t < 8; ++t) oacc[t][r] *= alpha;
            const int row = quad * 4 + r;
            Ps[w][row][0 * 16 + l16] = f2bf(p0);
            Ps[w][row][1 * 16 + l16] = f2bf(p1);
            Ps[w][row][2 * 16 + l16] = f2bf(p2);
            Ps[w][row][3 * 16 + l16] = f2bf(p3);
        }
        // wave-private Ps: no __syncthreads needed (same-wave LDS ordering)

        // --- PV: O(16x128) += P(16x64) @ V(64x128)
        #pragma unroll
        for (int c = 0; c < 2; ++c) {
            bfrag pf = ld_frag(&Ps[w][l16][c * 32 + quad * 8]);
            #pragma unroll
            for (int t = 0; t < 8; ++t) {
                bfrag vf = ld_frag(&Vt[t * 16 + l16][c * 32 + quad * 8]);
                oacc[t] = __builtin_amdgcn_mfma_f32_16x16x32_bf16(
                    pf, vf, oacc[t], 0, 0, 0);
            }
        }
    }

    // --- epilogue
    #pragma unroll
    for (int r = 0; r < 4; ++r) {
        const float invl = 1.0f / lr[r];
        const int row = rbase + r;
        float* op = o + ((size_t)(b * SS + row) * QH + qh) * HD;
        #pragma unroll
        for (int t = 0; t < 8; ++t)
            op[t * 16 + l16] = oacc[t][r] * invl;
    }
}

// ---------------------------------------------------------------------------
// Kernel 4: output projection (fp32 GEMM). o_pre[4096,2048] @ Wo[2048,2048].
// ---------------------------------------------------------------------------
__global__ __launch_bounds__(256) void oproj_kernel(
    const float* __restrict__ A, const float* __restrict__ W,
    float* __restrict__ C)
{
    const int cb = blockIdx.x * 64;
    const int m0 = blockIdx.y * 64;

    __shared__ float As[16][65];
    __shared__ float Ws[16][65];

    const int tid = threadIdx.x;
    const int tx = tid & 15, ty = tid >> 4;

    float acc[4][4] = {};

    for (int k0 = 0; k0 < 2048; k0 += 16) {
        #pragma unroll
        for (int it = 0; it < 4; ++it) {
            const int idx = tid + 256 * it;
            const int kk = idx & 15, r = idx >> 4;
            As[kk][r] = A[(size_t)(m0 + r) * 2048 + k0 + kk];
        }
        #pragma unroll
        for (int it = 0; it < 4; ++it) {
            const int idx = tid + 256 * it;
            const int c = idx & 63, kk = idx >> 6;
            Ws[kk][c] = W[(size_t)(k0 + kk) * 2048 + cb + c];
        }
        __syncthreads();
        #pragma unroll
        for (int kk = 0; kk < 16; ++kk) {
            float a[4], b[4];
            #pragma unroll
            for (int i = 0; i < 4; ++i) a[i] = As[kk][ty + 16 * i];
            #pragma unroll
            for (int j = 0; j < 4; ++j) b[j] = Ws[kk][tx + 16 * j];
            #pragma unroll
            for (int i = 0; i < 4; ++i)
                #pragma unroll
                for (int j = 0; j < 4; ++j) acc[i][j] += a[i] * b[j];
        }
        __syncthreads();
    }

    #pragma unroll
    for (int i = 0; i < 4; ++i)
        #pragma unroll
        for (int j = 0; j < 4; ++j)
            C[(size_t)(m0 + ty + 16 * i) * 2048 + cb + tx + 16 * j] = acc[i][j];
}

// ---------------------------------------------------------------------------
extern "C" void kernel_launch(void* const* d_in, const int* in_sizes, int n_in,
                              void* d_out, int out_size, void* d_ws,
                              size_t ws_size, hipStream_t stream)
{
    const float* x         = (const float*)d_in[0];
    const int*   positions = (const int*)d_in[1];
    const float* Wq        = (const float*)d_in[2];
    const float* Wk        = (const float*)d_in[3];
    const float* Wv        = (const float*)d_in[4];
    const float* Wo        = (const float*)d_in[5];
    float* out = (float*)d_out;

    // workspace layout (64 MB):
    //   [0,32MB)   qf32  (rope input)  -- later reused as o_pre fp32
    //   [32,40MB)  kf32  (rope input)
    //   [40,56MB)  qbf   bf16
    //   [56,60MB)  kbf   bf16
    //   [60,64MB)  vbf   bf16
    char* ws = (char*)d_ws;
    float*          qf32 = (float*)ws;                          // 32 MB
    float*          kf32 = (float*)(ws + (32u << 20));          //  8 MB
    unsigned short* qbf  = (unsigned short*)(ws + (40u << 20)); // 16 MB
    unsigned short* kbf  = (unsigned short*)(ws + (56u << 20)); //  4 MB
    unsigned short* vbf  = (unsigned short*)(ws + (60u << 20)); //  4 MB
    float*          opre = qf32;   // alias: qf32 dead after rope_cast

    dim3 g1(3072 / 64, (BB * SS) / 64);            // (48, 64)
    qkv_kernel<<<g1, 256, 0, stream>>>(x, Wq, Wk, Wv, qf32, kf32, vbf);

    const int pairs = BB * SS * (QH + NKV) * 64;
    rope_cast_kernel<<<(pairs + 255) / 256, 256, 0, stream>>>(
        qf32, kf32, qbf, kbf, positions);

    dim3 g2(SS / BM, BB * QH);                     // (32, 32)
    attn_kernel<<<g2, 256, 0, stream>>>(qbf, kbf, vbf, opre);

    dim3 g3(2048 / 64, (BB * SS) / 64);            // (32, 64)
    oproj_kernel<<<g3, 256, 0, stream>>>(opre, Wo, out);
}

// Round 3
// 662.180 us; speedup vs baseline: 5.4095x; 2.8749x over previous
//
#include <hip/hip_runtime.h>
#include <math.h>

#define BB 2
#define SS 2048
#define DD 2048
#define QH 16
#define NKV 4
#define HD 128
#define REP 4           // QH / NKV
#define NEG_INF_F (-1e9f)

typedef __bf16 bfrag __attribute__((ext_vector_type(8)));   // 4 VGPRs
typedef float  ffrag __attribute__((ext_vector_type(4)));   // 4 VGPRs

__device__ inline unsigned short f2bf(float f) {
    unsigned u = __builtin_bit_cast(unsigned, f);
    u += 0x7fff + ((u >> 16) & 1);          // round-to-nearest-even
    return (unsigned short)(u >> 16);
}
__device__ inline float bf2f(unsigned short u) {
    unsigned v = (unsigned)u << 16;
    return __builtin_bit_cast(float, v);
}
__device__ inline bfrag ld_frag(const unsigned short* p) {
    uint4 u = *(const uint4*)p;
    return __builtin_bit_cast(bfrag, u);
}
__device__ inline void async16(const void* g, void* l) {
    __builtin_amdgcn_global_load_lds(
        (const __attribute__((address_space(1))) unsigned int*)g,
        (__attribute__((address_space(3))) unsigned int*)l, 16, 0, 0);
}

// ---------------------------------------------------------------------------
// Kernel A: elementwise cast x fp32 -> bf16 (8 elems/thread).
// ---------------------------------------------------------------------------
__global__ void cast_x_kernel(const float* __restrict__ x,
                              unsigned short* __restrict__ xb, int n)
{
    const int i = (blockIdx.x * blockDim.x + threadIdx.x) * 8;
    if (i >= n) return;
    float4 a = *(const float4*)(x + i);
    float4 b = *(const float4*)(x + i + 4);
    unsigned short o[8];
    o[0] = f2bf(a.x); o[1] = f2bf(a.y); o[2] = f2bf(a.z); o[3] = f2bf(a.w);
    o[4] = f2bf(b.x); o[5] = f2bf(b.y); o[6] = f2bf(b.z); o[7] = f2bf(b.w);
    *(uint4*)(xb + i) = *(uint4*)o;
}

// ---------------------------------------------------------------------------
// Kernel B: tiled transpose-cast. in: [batch][R][C] fp32 -> out: [batch][C][R]
// bf16. 32x32 tiles via padded LDS; both sides coalesced.
// ---------------------------------------------------------------------------
__global__ __launch_bounds__(256) void tcast_kernel(
    const float* __restrict__ in, unsigned short* __restrict__ out,
    int R, int C)
{
    __shared__ float tile[32][33];
    const size_t bofs = (size_t)blockIdx.z * R * C;
    in  += bofs;
    out += bofs;
    const int c0 = blockIdx.x * 32, r0 = blockIdx.y * 32;
    const int tx = threadIdx.x & 31, ty = threadIdx.x >> 5;   // ty: 0..7
    #pragma unroll
    for (int k = 0; k < 4; ++k)
        tile[ty + 8 * k][tx] = in[(size_t)(r0 + ty + 8 * k) * C + c0 + tx];
    __syncthreads();
    #pragma unroll
    for (int k = 0; k < 4; ++k)
        out[(size_t)(c0 + ty + 8 * k) * R + r0 + tx] =
            f2bf(tile[tx][ty + 8 * k]);
}

// ---------------------------------------------------------------------------
// Kernel C: bf16 MFMA GEMM, m97 structure. C[4096, N] = A[4096,2048] @ B,
// with B supplied transposed: Bt[N][2048] bf16. 128x128 tile, BK=32,
// 4 waves x 4x4 16x16x32 MFMA. global_load_lds width-16 staging.
// mode 0: write fp32 to f_out[row*2048+col] (oproj).
// mode 1: qkv — col region selects q/k/v bf16 outputs.
// ---------------------------------------------------------------------------
__global__ __launch_bounds__(256) void gemm_bt_kernel(
    const unsigned short* __restrict__ A,
    const unsigned short* __restrict__ Bt,
    unsigned short* __restrict__ q_out, unsigned short* __restrict__ k_out,
    unsigned short* __restrict__ v_out, float* __restrict__ f_out,
    int mode)
{
    const int m0 = blockIdx.x * 128;
    const int n0 = blockIdx.y * 128;
    const int tid  = threadIdx.x;
    const int w    = tid >> 6, lane = tid & 63;
    const int l16  = lane & 15, quad = lane >> 4;
    const int wm = (w >> 1) * 64, wn = (w & 1) * 64;

    __shared__ unsigned short As[128 * 32];   // [m][k], 64 B rows
    __shared__ unsigned short Bs[128 * 32];   // [n][k]

    ffrag acc[4][4];
    #pragma unroll
    for (int mi = 0; mi < 4; ++mi)
        #pragma unroll
        for (int ni = 0; ni < 4; ++ni)
            acc[mi][ni] = (ffrag){0.f, 0.f, 0.f, 0.f};

    for (int k0 = 0; k0 < 2048; k0 += 32) {
        __syncthreads();   // prior iteration's fragment reads complete
        #pragma unroll
        for (int j = 0; j < 2; ++j) {
            const int i   = (j * 4 + w) * 64 + lane;   // chunk 0..511
            const int row = i >> 2, seg = i & 3;
            async16(&A [(size_t)(m0 + row) * 2048 + k0 + seg * 8],
                    (char*)As + i * 16);
            async16(&Bt[(size_t)(n0 + row) * 2048 + k0 + seg * 8],
                    (char*)Bs + i * 16);
        }
        __syncthreads();   // staging drained (compiler emits vmcnt(0))

        bfrag af[4], bfr[4];
        #pragma unroll
        for (int mi = 0; mi < 4; ++mi)
            af[mi] = ld_frag(&As[(wm + mi * 16 + l16) * 32 + quad * 8]);
        #pragma unroll
        for (int ni = 0; ni < 4; ++ni)
            bfr[ni] = ld_frag(&Bs[(wn + ni * 16 + l16) * 32 + quad * 8]);
        #pragma unroll
        for (int mi = 0; mi < 4; ++mi)
            #pragma unroll
            for (int ni = 0; ni < 4; ++ni)
                acc[mi][ni] = __builtin_amdgcn_mfma_f32_16x16x32_bf16(
                    af[mi], bfr[ni], acc[mi][ni], 0, 0, 0);
    }

    // epilogue: C layout row = quad*4+r, col = l16 within each 16x16 tile
    if (mode == 0) {
        #pragma unroll
        for (int mi = 0; mi < 4; ++mi)
            #pragma unroll
            for (int ni = 0; ni < 4; ++ni) {
                const int col = n0 + wn + ni * 16 + l16;
                #pragma unroll
                for (int r = 0; r < 4; ++r) {
                    const int row = m0 + wm + mi * 16 + quad * 4 + r;
                    f_out[(size_t)row * 2048 + col] = acc[mi][ni][r];
                }
            }
    } else {
        unsigned short* dst;
        int colbase, stride;
        if (n0 < 2048)      { dst = q_out; colbase = n0;        stride = 2048; }
        else if (n0 < 2560) { dst = k_out; colbase = n0 - 2048; stride = 512;  }
        else                { dst = v_out; colbase = n0 - 2560; stride = 512;  }
        #pragma unroll
        for (int mi = 0; mi < 4; ++mi)
            #pragma unroll
            for (int ni = 0; ni < 4; ++ni) {
                const int col = colbase + wn + ni * 16 + l16;
                #pragma unroll
                for (int r = 0; r < 4; ++r) {
                    const int row = m0 + wm + mi * 16 + quad * 4 + r;
                    dst[(size_t)row * stride + col] = f2bf(acc[mi][ni][r]);
                }
            }
    }
}

// ---------------------------------------------------------------------------
// Kernel D: RoPE in-place on bf16 q and k.
// ---------------------------------------------------------------------------
__global__ void rope_kernel(unsigned short* __restrict__ q,
                            unsigned short* __restrict__ k,
                            const int* __restrict__ positions)
{
    const int qpairs = BB * SS * QH * 64;
    const int kpairs = BB * SS * NKV * 64;
    int idx = blockIdx.x * blockDim.x + threadIdx.x;
    unsigned short* base;
    int nh;
    if (idx < qpairs) { base = q; nh = QH; }
    else {
        idx -= qpairs;
        if (idx >= kpairs) return;
        base = k; nh = NKV;
    }
    const int hh   = idx & 63;
    const int rest = idx >> 6;
    const int head = rest % nh;
    const int bs   = rest / nh;
    const int s    = bs % SS;

    unsigned short* p = base + ((size_t)bs * nh + head) * HD;
    const float pos = (float)positions[s];
    const float inv_ts = powf(10000.0f, -(float)hh * (1.0f / 64.0f));
    const float angle = pos * inv_ts;
    const float sn = sinf(angle), cs = cosf(angle);
    const float x1 = bf2f(p[hh]), x2 = bf2f(p[hh + 64]);
    p[hh]      = f2bf(x1 * cs - x2 * sn);
    p[hh + 64] = f2bf(x2 * cs + x1 * sn);
}

// ---------------------------------------------------------------------------
// Kernel E: causal flash attention, bf16 MFMA (16x16x32), GQA. Output bf16.
// ---------------------------------------------------------------------------
#define BM 64
#define BN 64
#define KPAD 136   // 128 + 8 bf16 pad
#define VPAD 72    // 64  + 8 bf16 pad

__global__ __launch_bounds__(256) void attn_kernel(
    const unsigned short* __restrict__ qb,
    const unsigned short* __restrict__ kb,
    const unsigned short* __restrict__ vb,
    unsigned short* __restrict__ o)
{
    const int s0 = blockIdx.x * BM;
    const int bh = blockIdx.y;
    const int b  = bh / QH, qh = bh % QH;
    const int n  = qh / REP;

    const int tid  = threadIdx.x;
    const int w    = tid >> 6;
    const int lane = tid & 63;
    const int l16  = lane & 15;
    const int quad = lane >> 4;

    __shared__ unsigned short Ks[BN][KPAD];
    __shared__ unsigned short Vt[HD][VPAD];
    __shared__ unsigned short Ps[4][16][VPAD];

    bfrag qf[4];
    {
        const int qrow = s0 + w * 16 + l16;
        const unsigned short* qp =
            qb + ((size_t)(b * SS + qrow) * QH + qh) * HD + quad * 8;
        #pragma unroll
        for (int c = 0; c < 4; ++c)
            qf[c] = ld_frag(qp + c * 32);
    }

    ffrag oacc[8];
    #pragma unroll
    for (int t = 0; t < 8; ++t) oacc[t] = (ffrag){0.f, 0.f, 0.f, 0.f};
    float mr[4], lr[4];
    #pragma unroll
    for (int r = 0; r < 4; ++r) { mr[r] = -1e30f; lr[r] = 0.0f; }
    const float scale = 0.08838834764831845f;
    const int rbase = s0 + w * 16 + quad * 4;

    for (int t0 = 0; t0 <= s0; t0 += BN) {
        __syncthreads();
        for (int idx = tid; idx < BN * 16; idx += 256) {
            const int r = idx >> 4, seg = idx & 15;
            const size_t ga =
                ((size_t)(b * SS + t0 + r) * NKV + n) * HD + seg * 8;
            uint4 kv = *(const uint4*)(kb + ga);
            *(uint4*)&Ks[r][seg * 8] = kv;
            uint4 vv = *(const uint4*)(vb + ga);
            const unsigned short* vs = (const unsigned short*)&vv;
            #pragma unroll
            for (int j = 0; j < 8; ++j) Vt[seg * 8 + j][r] = vs[j];
        }
        __syncthreads();

        ffrag sc[4];
        #pragma unroll
        for (int t = 0; t < 4; ++t) sc[t] = (ffrag){0.f, 0.f, 0.f, 0.f};
        #pragma unroll
        for (int c = 0; c < 4; ++c) {
            #pragma unroll
            for (int t = 0; t < 4; ++t) {
                bfrag kfr = ld_frag(&Ks[t * 16 + l16][c * 32 + quad * 8]);
                sc[t] = __builtin_amdgcn_mfma_f32_16x16x32_bf16(
                    qf[c], kfr, sc[t], 0, 0, 0);
            }
        }

        float sv[4][4];
        const bool need_mask = (t0 + BN - 1) > rbase;
        #pragma unroll
        for (int t = 0; t < 4; ++t) {
            const int col = t0 + t * 16 + l16;
            #pragma unroll
            for (int r = 0; r < 4; ++r) {
                float s = sc[t][r] * scale;
                if (need_mask && (col > rbase + r)) s = NEG_INF_F;
                sv[t][r] = s;
            }
        }
        #pragma unroll
        for (int r = 0; r < 4; ++r) {
            float tm = fmaxf(fmaxf(sv[0][r], sv[1][r]),
                             fmaxf(sv[2][r], sv[3][r]));
            #pragma unroll
            for (int off = 1; off < 16; off <<= 1)
                tm = fmaxf(tm, __shfl_xor(tm, off));
            const float mnew  = fmaxf(mr[r], tm);
            const float alpha = __expf(mr[r] - mnew);
            float p0 = __expf(sv[0][r] - mnew);
            float p1 = __expf(sv[1][r] - mnew);
            float p2 = __expf(sv[2][r] - mnew);
            float p3 = __expf(sv[3][r] - mnew);
            float ps = p0 + p1 + p2 + p3;
            #pragma unroll
            for (int off = 1; off < 16; off <<= 1)
                ps += __shfl_xor(ps, off);
            lr[r] = lr[r] * alpha + ps;
            mr[r] = mnew;
            #pragma unroll
            for (int t = 0; t < 8; ++t) oacc[t][r] *= alpha;
            const int row = quad * 4 + r;
            Ps[w][row][0 * 16 + l16] = f2bf(p0);
            Ps[w][row][1 * 16 + l16] = f2bf(p1);
            Ps[w][row][2 * 16 + l16] = f2bf(p2);
            Ps[w][row][3 * 16 + l16] = f2bf(p3);
        }

        #pragma unroll
        for (int c = 0; c < 2; ++c) {
            bfrag pf = ld_frag(&Ps[w][l16][c * 32 + quad * 8]);
            #pragma unroll
            for (int t = 0; t < 8; ++t) {
                bfrag vf = ld_frag(&Vt[t * 16 + l16][c * 32 + quad * 8]);
                oacc[t] = __builtin_amdgcn_mfma_f32_16x16x32_bf16(
                    pf, vf, oacc[t], 0, 0, 0);
            }
        }
    }

    #pragma unroll
    for (int r = 0; r < 4; ++r) {
        const float invl = 1.0f / lr[r];
        const int row = rbase + r;
        unsigned short* op = o + ((size_t)(b * SS + row) * QH + qh) * HD;
        #pragma unroll
        for (int t = 0; t < 8; ++t)
            op[t * 16 + l16] = f2bf(oacc[t][r] * invl);
    }
}

// ---------------------------------------------------------------------------
extern "C" void kernel_launch(void* const* d_in, const int* in_sizes, int n_in,
                              void* d_out, int out_size, void* d_ws,
                              size_t ws_size, hipStream_t stream)
{
    const float* x         = (const float*)d_in[0];
    const int*   positions = (const int*)d_in[1];
    const float* Wq        = (const float*)d_in[2];
    const float* Wk        = (const float*)d_in[3];
    const float* Wv        = (const float*)d_in[4];
    const float* Wo        = (const float*)d_in[5];
    float* out = (float*)d_out;

    // workspace (60 MB):
    //   [ 0,16)  xb  bf16 [4096][2048]      -- aliased by opre after qkv gemm
    //   [16,28)  Wqkvt bf16 [3072][2048]    (B^T: q heads 0..15, k 16..19, v 20..23)
    //   [28,36)  Wot bf16 [2048][2048]      (B^T)
    //   [36,52)  qbf bf16 [4096][16][128]
    //   [52,56)  kbf bf16 [4096][4][128]
    //   [56,60)  vbf bf16 [4096][4][128]
    char* ws = (char*)d_ws;
    unsigned short* xb    = (unsigned short*)ws;
    unsigned short* Wqkvt = (unsigned short*)(ws + (16u << 20));
    unsigned short* Wot   = (unsigned short*)(ws + (28u << 20));
    unsigned short* qbf   = (unsigned short*)(ws + (36u << 20));
    unsigned short* kbf   = (unsigned short*)(ws + (52u << 20));
    unsigned short* vbf   = (unsigned short*)(ws + (56u << 20));
    unsigned short* opre  = xb;   // alias: xb dead after qkv gemm

    const int nx = BB * SS * DD;                     // 8,388,608
    cast_x_kernel<<<nx / (8 * 256), 256, 0, stream>>>(x, xb, nx);

    // weights -> B^T bf16
    tcast_kernel<<<dim3(4, 64, 16), 256, 0, stream>>>(Wq, Wqkvt, 2048, 128);
    tcast_kernel<<<dim3(4, 64, 4), 256, 0, stream>>>(
        Wk, Wqkvt + (size_t)16 * 128 * 2048, 2048, 128);
    tcast_kernel<<<dim3(4, 64, 4), 256, 0, stream>>>(
        Wv, Wqkvt + (size_t)20 * 128 * 2048, 2048, 128);
    tcast_kernel<<<dim3(64, 64, 1), 256, 0, stream>>>(Wo, Wot, 2048, 2048);

    // qkv projection
    gemm_bt_kernel<<<dim3(32, 24), 256, 0, stream>>>(
        xb, Wqkvt, qbf, kbf, vbf, nullptr, 1);

    const int pairs = BB * SS * (QH + NKV) * 64;
    rope_kernel<<<(pairs + 255) / 256, 256, 0, stream>>>(qbf, kbf, positions);

    dim3 g2(SS / BM, BB * QH);
    attn_kernel<<<g2, 256, 0, stream>>>(qbf, kbf, vbf, opre);

    // output projection
    gemm_bt_kernel<<<dim3(32, 16), 256, 0, stream>>>(
        opre, Wot, nullptr, nullptr, nullptr, out, 0);
}

// Round 4
// 433.410 us; speedup vs baseline: 8.2648x; 1.5278x over previous
//
#include <hip/hip_runtime.h>
#include <math.h>

#define BB 2
#define SS 2048
#define DD 2048
#define QH 16
#define NKV 4
#define HD 128
#define REP 4           // QH / NKV
#define NEG_INF_F (-1e9f)

typedef __bf16 bfrag __attribute__((ext_vector_type(8)));   // 4 VGPRs
typedef float  ffrag __attribute__((ext_vector_type(4)));   // 4 VGPRs

__device__ inline unsigned short f2bf(float f) {
    unsigned u = __builtin_bit_cast(unsigned, f);
    u += 0x7fff + ((u >> 16) & 1);          // round-to-nearest-even
    return (unsigned short)(u >> 16);
}
__device__ inline float bf2f(unsigned short u) {
    unsigned v = (unsigned)u << 16;
    return __builtin_bit_cast(float, v);
}
__device__ inline bfrag ld_frag(const unsigned short* p) {
    uint4 u = *(const uint4*)p;
    return __builtin_bit_cast(bfrag, u);
}
__device__ inline void async16(const void* g, void* l) {
    __builtin_amdgcn_global_load_lds(
        (const __attribute__((address_space(1))) unsigned int*)g,
        (__attribute__((address_space(3))) unsigned int*)l, 16, 0, 0);
}

// ---------------------------------------------------------------------------
// Kernel A: elementwise cast x fp32 -> bf16 (8 elems/thread).
// ---------------------------------------------------------------------------
__global__ void cast_x_kernel(const float* __restrict__ x,
                              unsigned short* __restrict__ xb, int n)
{
    const int i = (blockIdx.x * blockDim.x + threadIdx.x) * 8;
    if (i >= n) return;
    float4 a = *(const float4*)(x + i);
    float4 b = *(const float4*)(x + i + 4);
    unsigned short o[8];
    o[0] = f2bf(a.x); o[1] = f2bf(a.y); o[2] = f2bf(a.z); o[3] = f2bf(a.w);
    o[4] = f2bf(b.x); o[5] = f2bf(b.y); o[6] = f2bf(b.z); o[7] = f2bf(b.w);
    *(uint4*)(xb + i) = *(uint4*)o;
}

// ---------------------------------------------------------------------------
// Kernel B: tiled transpose-cast. in: [batch][R][C] fp32 -> out: [batch][C][R]
// bf16. 32x32 tiles via padded LDS; both sides coalesced.
// ---------------------------------------------------------------------------
__global__ __launch_bounds__(256) void tcast_kernel(
    const float* __restrict__ in, unsigned short* __restrict__ out,
    int R, int C)
{
    __shared__ float tile[32][33];
    const size_t bofs = (size_t)blockIdx.z * R * C;
    in  += bofs;
    out += bofs;
    const int c0 = blockIdx.x * 32, r0 = blockIdx.y * 32;
    const int tx = threadIdx.x & 31, ty = threadIdx.x >> 5;   // ty: 0..7
    #pragma unroll
    for (int k = 0; k < 4; ++k)
        tile[ty + 8 * k][tx] = in[(size_t)(r0 + ty + 8 * k) * C + c0 + tx];
    __syncthreads();
    #pragma unroll
    for (int k = 0; k < 4; ++k)
        out[(size_t)(c0 + ty + 8 * k) * R + r0 + tx] =
            f2bf(tile[tx][ty + 8 * k]);
}

// ---------------------------------------------------------------------------
// Kernel C: bf16 MFMA GEMM, m97 structure. 128x128 tile, BK=32, 4 waves x
// 4x4 16x16x32 MFMA, global_load_lds width-16 staging.
// mode 0: fp32 out [row][2048] (oproj).
// mode 1: qkv — q,k natural bf16; v stored TRANSPOSED to vt[b][n][h][s].
// ---------------------------------------------------------------------------
__global__ __launch_bounds__(256) void gemm_bt_kernel(
    const unsigned short* __restrict__ A,
    const unsigned short* __restrict__ Bt,
    unsigned short* __restrict__ q_out, unsigned short* __restrict__ k_out,
    unsigned short* __restrict__ vt_out, float* __restrict__ f_out,
    int mode)
{
    const int m0 = blockIdx.x * 128;
    const int n0 = blockIdx.y * 128;
    const int tid  = threadIdx.x;
    const int w    = tid >> 6, lane = tid & 63;
    const int l16  = lane & 15, quad = lane >> 4;
    const int wm = (w >> 1) * 64, wn = (w & 1) * 64;

    __shared__ unsigned short As[128 * 32];   // [m][k], 64 B rows
    __shared__ unsigned short Bs[128 * 32];   // [n][k]

    ffrag acc[4][4];
    #pragma unroll
    for (int mi = 0; mi < 4; ++mi)
        #pragma unroll
        for (int ni = 0; ni < 4; ++ni)
            acc[mi][ni] = (ffrag){0.f, 0.f, 0.f, 0.f};

    for (int k0 = 0; k0 < 2048; k0 += 32) {
        __syncthreads();
        #pragma unroll
        for (int j = 0; j < 2; ++j) {
            const int i   = (j * 4 + w) * 64 + lane;   // chunk 0..511
            const int row = i >> 2, seg = i & 3;
            async16(&A [(size_t)(m0 + row) * 2048 + k0 + seg * 8],
                    (char*)As + i * 16);
            async16(&Bt[(size_t)(n0 + row) * 2048 + k0 + seg * 8],
                    (char*)Bs + i * 16);
        }
        __syncthreads();

        bfrag af[4], bfr[4];
        #pragma unroll
        for (int mi = 0; mi < 4; ++mi)
            af[mi] = ld_frag(&As[(wm + mi * 16 + l16) * 32 + quad * 8]);
        #pragma unroll
        for (int ni = 0; ni < 4; ++ni)
            bfr[ni] = ld_frag(&Bs[(wn + ni * 16 + l16) * 32 + quad * 8]);
        #pragma unroll
        for (int mi = 0; mi < 4; ++mi)
            #pragma unroll
            for (int ni = 0; ni < 4; ++ni)
                acc[mi][ni] = __builtin_amdgcn_mfma_f32_16x16x32_bf16(
                    af[mi], bfr[ni], acc[mi][ni], 0, 0, 0);
    }

    if (mode == 0) {
        #pragma unroll
        for (int mi = 0; mi < 4; ++mi)
            #pragma unroll
            for (int ni = 0; ni < 4; ++ni) {
                const int col = n0 + wn + ni * 16 + l16;
                #pragma unroll
                for (int r = 0; r < 4; ++r) {
                    const int row = m0 + wm + mi * 16 + quad * 4 + r;
                    f_out[(size_t)row * 2048 + col] = acc[mi][ni][r];
                }
            }
    } else if (n0 < 2560) {
        unsigned short* dst;
        int colbase, stride;
        if (n0 < 2048)      { dst = q_out; colbase = n0;        stride = 2048; }
        else                { dst = k_out; colbase = n0 - 2048; stride = 512;  }
        #pragma unroll
        for (int mi = 0; mi < 4; ++mi)
            #pragma unroll
            for (int ni = 0; ni < 4; ++ni) {
                const int col = colbase + wn + ni * 16 + l16;
                #pragma unroll
                for (int r = 0; r < 4; ++r) {
                    const int row = m0 + wm + mi * 16 + quad * 4 + r;
                    dst[(size_t)row * stride + col] = f2bf(acc[mi][ni][r]);
                }
            }
    } else {
        // v region: transposed store vt[b][n][h][s], 4 bf16 (s..s+3) packed
        const int c3 = n0 - 2560;
        #pragma unroll
        for (int mi = 0; mi < 4; ++mi)
            #pragma unroll
            for (int ni = 0; ni < 4; ++ni) {
                const int col = c3 + wn + ni * 16 + l16;   // 0..511
                const int nh = col >> 7, h = col & 127;
                const int row0 = m0 + wm + mi * 16 + quad * 4;
                const int b = row0 >> 11, s = row0 & 2047;
                unsigned short pk[4];
                #pragma unroll
                for (int r = 0; r < 4; ++r) pk[r] = f2bf(acc[mi][ni][r]);
                *(uint2*)&vt_out[(((size_t)b * NKV + nh) * HD + h) * SS + s] =
                    *(uint2*)pk;
            }
    }
}

// ---------------------------------------------------------------------------
// Kernel D: RoPE in-place on bf16 q and k.
// ---------------------------------------------------------------------------
__global__ void rope_kernel(unsigned short* __restrict__ q,
                            unsigned short* __restrict__ k,
                            const int* __restrict__ positions)
{
    const int qpairs = BB * SS * QH * 64;
    const int kpairs = BB * SS * NKV * 64;
    int idx = blockIdx.x * blockDim.x + threadIdx.x;
    unsigned short* base;
    int nh;
    if (idx < qpairs) { base = q; nh = QH; }
    else {
        idx -= qpairs;
        if (idx >= kpairs) return;
        base = k; nh = NKV;
    }
    const int hh   = idx & 63;
    const int rest = idx >> 6;
    const int head = rest % nh;
    const int bs   = rest / nh;
    const int s    = bs % SS;

    unsigned short* p = base + ((size_t)bs * nh + head) * HD;
    const float pos = (float)positions[s];
    const float inv_ts = powf(10000.0f, -(float)hh * (1.0f / 64.0f));
    const float angle = pos * inv_ts;
    const float sn = sinf(angle), cs = cosf(angle);
    const float x1 = bf2f(p[hh]), x2 = bf2f(p[hh + 64]);
    p[hh]      = f2bf(x1 * cs - x2 * sn);
    p[hh + 64] = f2bf(x2 * cs + x1 * sn);
}

// ---------------------------------------------------------------------------
// Kernel E: causal flash attention v2.
//  - block bx handles Q-tile pair {bx, 31-bx}: 33 tile-units per block
//    (perfect causal balance); staged K/V tile shared by both Q-tiles.
//  - K LDS [hchunk][t][32], V^T LDS [tchunk][h][32]: m97 chunk layout,
//    async16 staging (lane-sequential LDS writes = conflict-free).
//  - P per-wave [kchunk][16][34] (pad-17-word rows, ~2-way max).
// ---------------------------------------------------------------------------
struct TileState {
    bfrag qf[4];
    ffrag oacc[8];
    float mr[4], lr[4];
};

__device__ __forceinline__ void attn_tile_step(
    TileState& st,
    const unsigned short (&Ks)[4][64][32],
    const unsigned short (&Vs)[2][128][32],
    unsigned short (&Psw)[2][16][34],
    int l16, int quad, bool diag, int rbase, int t0)
{
    const float scale = 0.08838834764831845f;   // 1/sqrt(128)
    ffrag sc[4];
    #pragma unroll
    for (int t = 0; t < 4; ++t) sc[t] = (ffrag){0.f, 0.f, 0.f, 0.f};
    #pragma unroll
    for (int c = 0; c < 4; ++c) {
        #pragma unroll
        for (int t = 0; t < 4; ++t) {
            bfrag kfr = ld_frag(&Ks[c][t * 16 + l16][quad * 8]);
            sc[t] = __builtin_amdgcn_mfma_f32_16x16x32_bf16(
                st.qf[c], kfr, sc[t], 0, 0, 0);
        }
    }

    float sv[4][4];
    #pragma unroll
    for (int t = 0; t < 4; ++t) {
        const int col = t0 + t * 16 + l16;
        #pragma unroll
        for (int r = 0; r < 4; ++r) {
            float s = sc[t][r] * scale;
            if (diag && (col > rbase + r)) s = NEG_INF_F;
            sv[t][r] = s;
        }
    }
    #pragma unroll
    for (int r = 0; r < 4; ++r) {
        float tm = fmaxf(fmaxf(sv[0][r], sv[1][r]),
                         fmaxf(sv[2][r], sv[3][r]));
        #pragma unroll
        for (int off = 1; off < 16; off <<= 1)
            tm = fmaxf(tm, __shfl_xor(tm, off));
        const float mnew  = fmaxf(st.mr[r], tm);
        const float alpha = __expf(st.mr[r] - mnew);
        float p0 = __expf(sv[0][r] - mnew);
        float p1 = __expf(sv[1][r] - mnew);
        float p2 = __expf(sv[2][r] - mnew);
        float p3 = __expf(sv[3][r] - mnew);
        float ps = p0 + p1 + p2 + p3;
        #pragma unroll
        for (int off = 1; off < 16; off <<= 1)
            ps += __shfl_xor(ps, off);
        st.lr[r] = st.lr[r] * alpha + ps;
        st.mr[r] = mnew;
        #pragma unroll
        for (int t = 0; t < 8; ++t) st.oacc[t][r] *= alpha;
        const int row = quad * 4 + r;
        Psw[0][row][0 * 16 + l16] = f2bf(p0);
        Psw[0][row][1 * 16 + l16] = f2bf(p1);
        Psw[1][row][0 * 16 + l16] = f2bf(p2);
        Psw[1][row][1 * 16 + l16] = f2bf(p3);
    }
    // wave-private Ps: same-wave LDS ordering, no barrier needed
    #pragma unroll
    for (int c = 0; c < 2; ++c) {
        bfrag pf = ld_frag(&Psw[c][l16][quad * 8]);
        #pragma unroll
        for (int t = 0; t < 8; ++t) {
            bfrag vf = ld_frag(&Vs[c][t * 16 + l16][quad * 8]);
            st.oacc[t] = __builtin_amdgcn_mfma_f32_16x16x32_bf16(
                pf, vf, st.oacc[t], 0, 0, 0);
        }
    }
}

__global__ __launch_bounds__(256, 2) void attn_kernel(
    const unsigned short* __restrict__ qb,
    const unsigned short* __restrict__ kb,
    const unsigned short* __restrict__ vt,
    unsigned short* __restrict__ o)
{
    const int bh = blockIdx.y;
    const int b  = bh / QH, qh = bh % QH;
    const int n  = qh / REP;
    const int s0a = blockIdx.x * 64;           // light tile (0..15)
    const int s0b = (31 - blockIdx.x) * 64;    // heavy tile (16..31)

    const int tid  = threadIdx.x;
    const int w    = tid >> 6;
    const int lane = tid & 63;
    const int l16  = lane & 15;
    const int quad = lane >> 4;

    __shared__ unsigned short Ks[4][64][32];    // 16 KB
    __shared__ unsigned short Vs[2][128][32];   // 16 KB
    __shared__ unsigned short Ps[4][2][16][34]; // 8.7 KB

    TileState sa, sb;
    {
        const unsigned short* qpa =
            qb + ((size_t)(b * SS + s0a + w * 16 + l16) * QH + qh) * HD + quad * 8;
        const unsigned short* qpb =
            qb + ((size_t)(b * SS + s0b + w * 16 + l16) * QH + qh) * HD + quad * 8;
        #pragma unroll
        for (int c = 0; c < 4; ++c) {
            sa.qf[c] = ld_frag(qpa + c * 32);
            sb.qf[c] = ld_frag(qpb + c * 32);
        }
    }
    #pragma unroll
    for (int t = 0; t < 8; ++t) {
        sa.oacc[t] = (ffrag){0.f, 0.f, 0.f, 0.f};
        sb.oacc[t] = (ffrag){0.f, 0.f, 0.f, 0.f};
    }
    #pragma unroll
    for (int r = 0; r < 4; ++r) {
        sa.mr[r] = -1e30f; sa.lr[r] = 0.0f;
        sb.mr[r] = -1e30f; sb.lr[r] = 0.0f;
    }

    const unsigned short* kbase = kb + (size_t)b * (SS * NKV * HD) + n * HD;
    const unsigned short* vbase = vt + ((size_t)b * NKV + n) * HD * SS;

    for (int t0 = 0; t0 <= s0b; t0 += 64) {
        __syncthreads();   // previous iteration's fragment reads complete
        #pragma unroll
        for (int j = 0; j < 4; ++j) {
            const int s = j * 256 + tid;
            {   // K tile: [c=h-chunk][t][seg], LDS offset = s*16
                const int c = s >> 8, t = (s >> 2) & 63, seg = s & 3;
                async16(kbase + (size_t)(t0 + t) * (NKV * HD) + c * 32 + seg * 8,
                        (char*)Ks + s * 16);
            }
            {   // V^T tile: [c=t-chunk][h][seg], LDS offset = s*16
                const int c = s >> 9, h = (s >> 2) & 127, seg = s & 3;
                async16(vbase + (size_t)h * SS + t0 + c * 32 + seg * 8,
                        (char*)Vs + s * 16);
            }
        }
        __syncthreads();   // staging drained

        attn_tile_step(sb, Ks, Vs, Ps[w], l16, quad,
                       t0 == s0b, s0b + w * 16 + quad * 4, t0);
        if (t0 <= s0a)
            attn_tile_step(sa, Ks, Vs, Ps[w], l16, quad,
                           t0 == s0a, s0a + w * 16 + quad * 4, t0);
    }

    #pragma unroll
    for (int r = 0; r < 4; ++r) {
        const float invla = 1.0f / sa.lr[r];
        const float invlb = 1.0f / sb.lr[r];
        const int rowa = s0a + w * 16 + quad * 4 + r;
        const int rowb = s0b + w * 16 + quad * 4 + r;
        unsigned short* opa = o + ((size_t)(b * SS + rowa) * QH + qh) * HD;
        unsigned short* opb = o + ((size_t)(b * SS + rowb) * QH + qh) * HD;
        #pragma unroll
        for (int t = 0; t < 8; ++t) {
            opa[t * 16 + l16] = f2bf(sa.oacc[t][r] * invla);
            opb[t * 16 + l16] = f2bf(sb.oacc[t][r] * invlb);
        }
    }
}

// ---------------------------------------------------------------------------
extern "C" void kernel_launch(void* const* d_in, const int* in_sizes, int n_in,
                              void* d_out, int out_size, void* d_ws,
                              size_t ws_size, hipStream_t stream)
{
    const float* x         = (const float*)d_in[0];
    const int*   positions = (const int*)d_in[1];
    const float* Wq        = (const float*)d_in[2];
    const float* Wk        = (const float*)d_in[3];
    const float* Wv        = (const float*)d_in[4];
    const float* Wo        = (const float*)d_in[5];
    float* out = (float*)d_out;

    // workspace (60 MB):
    //   [ 0,16)  xb  bf16 [4096][2048]      -- aliased by opre after qkv gemm
    //   [16,28)  Wqkvt bf16 [3072][2048]    (B^T)
    //   [28,36)  Wot bf16 [2048][2048]      (B^T)
    //   [36,52)  qbf bf16 [4096][16][128]
    //   [52,56)  kbf bf16 [4096][4][128]
    //   [56,60)  vtb bf16 [2][4][128][2048] (V^T: [b][n][h][s])
    char* ws = (char*)d_ws;
    unsigned short* xb    = (unsigned short*)ws;
    unsigned short* Wqkvt = (unsigned short*)(ws + (16u << 20));
    unsigned short* Wot   = (unsigned short*)(ws + (28u << 20));
    unsigned short* qbf   = (unsigned short*)(ws + (36u << 20));
    unsigned short* kbf   = (unsigned short*)(ws + (52u << 20));
    unsigned short* vtb   = (unsigned short*)(ws + (56u << 20));
    unsigned short* opre  = xb;   // alias: xb dead after qkv gemm

    const int nx = BB * SS * DD;                     // 8,388,608
    cast_x_kernel<<<nx / (8 * 256), 256, 0, stream>>>(x, xb, nx);

    // weights -> B^T bf16
    tcast_kernel<<<dim3(4, 64, 16), 256, 0, stream>>>(Wq, Wqkvt, 2048, 128);
    tcast_kernel<<<dim3(4, 64, 4), 256, 0, stream>>>(
        Wk, Wqkvt + (size_t)16 * 128 * 2048, 2048, 128);
    tcast_kernel<<<dim3(4, 64, 4), 256, 0, stream>>>(
        Wv, Wqkvt + (size_t)20 * 128 * 2048, 2048, 128);
    tcast_kernel<<<dim3(64, 64, 1), 256, 0, stream>>>(Wo, Wot, 2048, 2048);

    // qkv projection (v stored transposed)
    gemm_bt_kernel<<<dim3(32, 24), 256, 0, stream>>>(
        xb, Wqkvt, qbf, kbf, vtb, nullptr, 1);

    const int pairs = BB * SS * (QH + NKV) * 64;
    rope_kernel<<<(pairs + 255) / 256, 256, 0, stream>>>(qbf, kbf, positions);

    // attention: paired causal tiles, 512 blocks
    dim3 g2(16, BB * QH);
    attn_kernel<<<g2, 256, 0, stream>>>(qbf, kbf, vtb, opre);

    // output projection
    gemm_bt_kernel<<<dim3(32, 16), 256, 0, stream>>>(
        opre, Wot, nullptr, nullptr, nullptr, out, 0);
}